// Round 10
// baseline (24.169 us; speedup 1.0000x reference)
//
#include <hip/hip_runtime.h>
#include <cfloat>

// Problem constants: B=32, C=256, L=512, N=1024, S=8
constexpr int Bc = 32;
constexpr int Cc = 256;
constexpr int Lc = 512;
constexpr int Nc = 1024;
constexpr int Sc = 8;

constexpr int CT     = 16;    // channels per block
constexpr int STRIDE = 516;   // LDS row stride (floats); row base 2064B = 16B-aligned

typedef float f4 __attribute__((ext_vector_type(4)));

// masked max over chunk elements [lo, hi) (cndmask, no branch)
__device__ __forceinline__ float chunkmax(f4 v, int lo, int hi, float m) {
    float a0 = (lo <= 0 && 0 < hi) ? v.x : -FLT_MAX;
    float a1 = (lo <= 1 && 1 < hi) ? v.y : -FLT_MAX;
    float a2 = (lo <= 2 && 2 < hi) ? v.z : -FLT_MAX;
    float a3 = (lo <= 3 && 3 < hi) ? v.w : -FLT_MAX;
    return fmaxf(fmaxf(m, fmaxf(a0, a1)), fmaxf(a2, a3));
}

// Block = (batch b, 16-channel tile) — R8's proven phase/sync skeleton:
// ballot compaction, then staging load->ds_write in-loop (now also emitting a
// free 4-wide level-1 max from the same registers), one barrier, prefix,
// list writes, barrier, pyramid bin-walk.
__global__ __launch_bounds__(256) void roi_pool_pyr2(
    const float* __restrict__ sentences,   // (B, C, L)
    const int*   __restrict__ rois,        // (N, 2)
    const int*   __restrict__ roi_idx,     // (N,)
    float*       __restrict__ out)         // (N, C, S)
{
    __shared__ float rowbuf[CT * STRIDE];  // 33,024 B
    __shared__ float lvl1[CT * 128];       // 8,192 B: lvl1[r*128+q] = max(row[4q..4q+4))
    __shared__ int   list[Nc];             // 4 KB (worst-case safe)
    __shared__ int   wcnt[16];

    const int bid  = blockIdx.x;           // 0..511
    const int b    = bid >> 4;             // batch
    const int c0   = (bid & 15) * CT;      // channel tile base
    const int tid  = threadIdx.x;
    const int lane = tid & 63;
    const int w    = tid >> 6;             // wave 0..3

    // ---- ballot compaction scan (verbatim R8) ----
    int myidx[4], mypos[4];
    #pragma unroll
    for (int q = 0; q < 4; ++q) {
        const int i = q * 256 + tid;
        const int v = roi_idx[i];
        const unsigned long long mask = __ballot(v == b);
        mypos[q] = __popcll(mask & ((1ull << lane) - 1ull));
        myidx[q] = (v == b) ? i : -1;
        if (lane == 0) wcnt[q * 4 + w] = __popcll(mask);
    }

    // ---- staging: load -> ds_write in-loop (R8 pattern) + level-1 pyramid ----
    {
        const f4* src = (const f4*)(sentences + ((size_t)b * Cc + c0) * Lc);
        #pragma unroll
        for (int i = 0; i < (CT * Lc / 4) / 256; ++i) {   // 8 chunks/thread
            const int idx = tid + i * 256;                // 0..2047
            const int r   = idx >> 7;                     // row 0..15
            const int q   = idx & 127;                    // f4 slot
            f4 v = src[r * (Lc / 4) + q];                 // coalesced 1KB/wave
            *(f4*)(rowbuf + r * STRIDE + 4 * q) = v;      // aligned ds_write_b128
            lvl1[r * 128 + q] = fmaxf(fmaxf(v.x, v.y), fmaxf(v.z, v.w));
        }
    }
    __syncthreads();   // wcnt + rowbuf + lvl1 visible

    // ---- deterministic prefix over wcnt (verbatim R8) ----
    int wb0 = 0, wb1 = 0, wb2 = 0, wb3 = 0, run = 0;
    #pragma unroll
    for (int t = 0; t < 16; ++t) {
        if (t == w)      wb0 = run;
        if (t == 4 + w)  wb1 = run;
        if (t == 8 + w)  wb2 = run;
        if (t == 12 + w) wb3 = run;
        run += wcnt[t];
    }
    const int m = run;                     // bucket size for batch b

    if (myidx[0] >= 0) list[wb0 + mypos[0]] = myidx[0];
    if (myidx[1] >= 0) list[wb1 + mypos[1]] = myidx[1];
    if (myidx[2] >= 0) list[wb2 + mypos[2]] = myidx[2];
    if (myidx[3] >= 0) list[wb3 + mypos[3]] = myidx[3];
    __syncthreads();   // list visible

    // ---- bin maxes: rp-group (2 waves) per item; lane = (cl, j) ----
    const int rp = tid >> 7;               // 0/1
    const int cl = (tid >> 3) & 15;        // channel within tile
    const int j  = tid & 7;                // bin
    const float* row = rowbuf + cl * STRIDE;
    const float* lv  = lvl1 + cl * 128;

    for (int i = rp; i < m; i += 2) {
        const int n  = list[i];            // wave-uniform
        const int x1 = rois[2 * n];
        const int x2 = rois[2 * n + 1];
        const int lr = x2 - x1;            // 1..512
        const int s  = x1 + ((j * lr) >> 3);
        const int e  = x1 + (((j + 1) * lr + Sc - 1) >> 3);   // > s always

        const int qs = s >> 2;
        const int qe = e >> 2;

        // head chunk [s, min(e, 4qs+4)) — masked f4
        f4 hv = *(const f4*)(row + 4 * qs);
        float mm = chunkmax(hv, s & 3, min(4, e - 4 * qs), -FLT_MAX);

        // interior full 4-blocks via level-1
        for (int q = qs + 1; q < qe; ++q)
            mm = fmaxf(mm, lv[q]);

        // tail partial block (exists only if e&3 and distinct from head)
        if ((e & 3) && qe > qs) {          // e&3!=0 -> e<=511 -> qe<=127: in-bounds
            f4 tv = *(const f4*)(row + 4 * qe);
            mm = chunkmax(tv, 0, e & 3, mm);
        }

        // wave lanes (cl,j) -> 64 consecutive floats: coalesced 256B store
        out[(size_t)n * (Cc * Sc) + (c0 + cl) * Sc + j] = mm;
    }
}

extern "C" void kernel_launch(void* const* d_in, const int* in_sizes, int n_in,
                              void* d_out, int out_size, void* d_ws, size_t ws_size,
                              hipStream_t stream) {
    const float* sentences = (const float*)d_in[0];
    const int*   rois      = (const int*)d_in[1];
    const int*   roi_idx   = (const int*)d_in[2];
    float*       out       = (float*)d_out;

    roi_pool_pyr2<<<Bc * (Cc / CT), 256, 0, stream>>>(sentences, rois, roi_idx, out);
}

// Round 11
// 19.475 us; speedup vs baseline: 1.2410x; 1.2410x over previous
//
#include <hip/hip_runtime.h>
#include <cfloat>

// Problem constants: B=32, C=256, L=512, N=1024, S=8
constexpr int Bc = 32;
constexpr int Cc = 256;
constexpr int Lc = 512;
constexpr int Nc = 1024;
constexpr int Sc = 8;

constexpr int CT      = 8;    // channels per block
constexpr int STRIDE  = 516;  // rowbuf stride (floats): 516%32==4 spreads channel banks
constexpr int LSTRIDE = 132;  // lvl1 stride (floats): 132%32==4 spreads channel banks

typedef float f4 __attribute__((ext_vector_type(4)));

// masked max over chunk elements [lo, hi) (cndmask, no branch)
__device__ __forceinline__ float chunkmax(f4 v, int lo, int hi, float m) {
    float a0 = (lo <= 0 && 0 < hi) ? v.x : -FLT_MAX;
    float a1 = (lo <= 1 && 1 < hi) ? v.y : -FLT_MAX;
    float a2 = (lo <= 2 && 2 < hi) ? v.z : -FLT_MAX;
    float a3 = (lo <= 3 && 3 < hi) ? v.w : -FLT_MAX;
    return fmaxf(fmaxf(m, fmaxf(a0, a1)), fmaxf(a2, a3));
}

// Block = (batch b, 8-channel tile); 1024 blocks, ~25 KB LDS -> 4 resident/CU,
// 16 waves/CU. R10's deterministic skeleton; lvl1 pyramid with padded stride;
// walk = one wave per bucket item (lane = (cl, j)).
__global__ __launch_bounds__(256) void roi_pool_pyr3(
    const float* __restrict__ sentences,   // (B, C, L)
    const int*   __restrict__ rois,        // (N, 2)
    const int*   __restrict__ roi_idx,     // (N,)
    float*       __restrict__ out)         // (N, C, S)
{
    __shared__ float rowbuf[CT * STRIDE];   // 16,512 B
    __shared__ float lvl1[CT * LSTRIDE];    // 4,224 B: lvl1[r*132+q] = max(row[4q..4q+4))
    __shared__ int   list[Nc];              // 4 KB (worst-case safe)
    __shared__ int   wcnt[16];

    const int bid  = blockIdx.x;           // 0..1023
    const int b    = bid >> 5;             // batch
    const int c0   = (bid & 31) * CT;      // channel tile base
    const int tid  = threadIdx.x;
    const int lane = tid & 63;
    const int w    = tid >> 6;             // wave 0..3

    // ---- ballot compaction scan (R8/R10 proven) ----
    int myidx[4], mypos[4];
    #pragma unroll
    for (int q = 0; q < 4; ++q) {
        const int i = q * 256 + tid;
        const int v = roi_idx[i];
        const unsigned long long mask = __ballot(v == b);
        mypos[q] = __popcll(mask & ((1ull << lane) - 1ull));
        myidx[q] = (v == b) ? i : -1;
        if (lane == 0) wcnt[q * 4 + w] = __popcll(mask);
    }

    // ---- staging: load -> ds_write in-loop + level-1 pyramid ----
    {
        const f4* src = (const f4*)(sentences + ((size_t)b * Cc + c0) * Lc);
        #pragma unroll
        for (int i = 0; i < (CT * Lc / 4) / 256; ++i) {   // 4 chunks/thread
            const int idx = tid + i * 256;                // 0..1023
            const int r   = idx >> 7;                     // row 0..7
            const int q   = idx & 127;                    // f4 slot
            f4 v = src[r * (Lc / 4) + q];                 // coalesced 1KB/wave
            *(f4*)(rowbuf + r * STRIDE + 4 * q) = v;      // aligned ds_write_b128
            lvl1[r * LSTRIDE + q] = fmaxf(fmaxf(v.x, v.y), fmaxf(v.z, v.w));
        }
    }
    __syncthreads();   // wcnt + rowbuf + lvl1 visible

    // ---- deterministic prefix over wcnt (verbatim) ----
    int wb0 = 0, wb1 = 0, wb2 = 0, wb3 = 0, run = 0;
    #pragma unroll
    for (int t = 0; t < 16; ++t) {
        if (t == w)      wb0 = run;
        if (t == 4 + w)  wb1 = run;
        if (t == 8 + w)  wb2 = run;
        if (t == 12 + w) wb3 = run;
        run += wcnt[t];
    }
    const int m = run;                     // bucket size for batch b

    if (myidx[0] >= 0) list[wb0 + mypos[0]] = myidx[0];
    if (myidx[1] >= 0) list[wb1 + mypos[1]] = myidx[1];
    if (myidx[2] >= 0) list[wb2 + mypos[2]] = myidx[2];
    if (myidx[3] >= 0) list[wb3 + mypos[3]] = myidx[3];
    __syncthreads();   // list visible

    // ---- bin maxes: wave w handles items w, w+4, ...; lane = (cl, j) ----
    const int cl = lane >> 3;              // channel within tile 0..7
    const int j  = lane & 7;               // bin
    const float* row = rowbuf + cl * STRIDE;
    const float* lv  = lvl1 + cl * LSTRIDE;

    for (int i = w; i < m; i += 4) {
        const int n  = list[i];            // wave-uniform
        const int x1 = rois[2 * n];
        const int x2 = rois[2 * n + 1];
        const int lr = x2 - x1;            // 1..512
        const int s  = x1 + ((j * lr) >> 3);
        const int e  = x1 + (((j + 1) * lr + Sc - 1) >> 3);   // > s always

        const int qs = s >> 2;
        const int qe = e >> 2;

        // head chunk [s, min(e, 4qs+4)) — masked f4
        f4 hv = *(const f4*)(row + 4 * qs);
        float mm = chunkmax(hv, s & 3, min(4, e - 4 * qs), -FLT_MAX);

        // interior full 4-blocks via level-1 (padded stride: ~2-way banks)
        for (int q = qs + 1; q < qe; ++q)
            mm = fmaxf(mm, lv[q]);

        // tail partial block (exists only if e&3 and distinct from head)
        if ((e & 3) && qe > qs) {          // e&3!=0 -> e<=511 -> qe<=127: in-bounds
            f4 tv = *(const f4*)(row + 4 * qe);
            mm = chunkmax(tv, 0, e & 3, mm);
        }

        // wave lanes (cl,j) -> 64 consecutive floats: coalesced 256B store
        out[(size_t)n * (Cc * Sc) + (c0 + cl) * Sc + j] = mm;
    }
}

extern "C" void kernel_launch(void* const* d_in, const int* in_sizes, int n_in,
                              void* d_out, int out_size, void* d_ws, size_t ws_size,
                              hipStream_t stream) {
    const float* sentences = (const float*)d_in[0];
    const int*   rois      = (const int*)d_in[1];
    const int*   roi_idx   = (const int*)d_in[2];
    float*       out       = (float*)d_out;

    roi_pool_pyr3<<<Bc * (Cc / CT), 256, 0, stream>>>(sentences, rois, roi_idx, out);
}